// Round 4
// baseline (319.392 us; speedup 1.0000x reference)
//
#include <hip/hip_runtime.h>
#include <hip/hip_bf16.h>

// SAGE reranker, bf16-MFMA + bucketed-CSR, round 4.
// Round-4 change: GEMM row-tile 128 -> 64 (grid 391 -> 782 blocks). Round 3 showed
// OccupancyPercent=12% / MfmaUtil=7.8% / VALUBusy=7.9% on GEMM0: grid starvation
// (1.5 blocks/CU). 64-row tiles + smaller LDS/acc -> ~3 blocks/CU (12 waves/CU).

#define DIN 256
#define DH 128
#define NPB 512        // nodes per bucket (dst>>9)
#define NBMAX 128      // max buckets (N<=65536)
#define EPB 4096       // edges per partition block
#define CAP 14336      // LDS adj window capacity (bucket edges ~8.2K expected)

typedef __attribute__((ext_vector_type(8))) short short8;
typedef __attribute__((ext_vector_type(4))) float float4v;

__device__ inline ushort f2b(float f){
  unsigned u = __float_as_uint(f);
  u = (u + 0x7fffu + ((u >> 16) & 1u)) >> 16;   // round-nearest-even
  return (ushort)u;
}
__device__ inline float blo(unsigned v){ return __uint_as_float(v << 16); }
__device__ inline float bhi(unsigned v){ return __uint_as_float(v & 0xffff0000u); }

// ---------------- CSR build (bucketed, coalesced writes only) ----------------
__global__ __launch_bounds__(256) void bucket_hist_kernel(
    const int* __restrict__ dst, int E, int NB, int* __restrict__ bucketCnt)
{
  __shared__ int hist[NBMAX];
  int t = threadIdx.x;
  for (int i=t;i<NB;i+=256) hist[i]=0;
  __syncthreads();
  int base = blockIdx.x * EPB;
  #pragma unroll
  for (int j=0;j<16;j++){
    int e = base + j*256 + t;
    if (e < E) atomicAdd(&hist[dst[e] >> 9], 1);
  }
  __syncthreads();
  for (int i=t;i<NB;i+=256) atomicAdd(&bucketCnt[i], hist[i]);
}

__global__ void scan_buckets_kernel(const int* __restrict__ bucketCnt, int NB, int E,
                                    int* __restrict__ bucketBase, int* __restrict__ bucketCur,
                                    int* __restrict__ off, int N)
{
  __shared__ int s[NBMAX];
  int t = threadIdx.x;  // NBMAX threads
  s[t] = (t < NB)? bucketCnt[t] : 0;
  __syncthreads();
  for (int st=1; st<NBMAX; st<<=1){
    int v = (t>=st)? s[t-st] : 0;
    __syncthreads();
    s[t] += v;
    __syncthreads();
  }
  int excl = (t>0)? s[t-1] : 0;
  if (t < NB){ bucketBase[t] = excl; bucketCur[t] = excl; }
  if (t == NB) bucketBase[NB] = E;
  if (t == 0) off[N] = E;
}

__global__ __launch_bounds__(256) void partition_kernel(
    const int* __restrict__ src, const int* __restrict__ dst, int E, int NB,
    int* __restrict__ bucketCur, int* __restrict__ pairS, int* __restrict__ pairD)
{
  __shared__ int hist[NBMAX], lbase[NBMAX], gbase[NBMAX], lcur[NBMAX], sc[NBMAX];
  __shared__ int ls[EPB], ld[EPB];
  int t = threadIdx.x;
  int base = blockIdx.x * EPB;
  int cnt = E - base; if (cnt > EPB) cnt = EPB;
  for (int i=t;i<NB;i+=256) hist[i]=0;
  __syncthreads();
  int myS[16], myD[16];
  #pragma unroll
  for (int j=0;j<16;j++){
    int e = base + j*256 + t;
    if (e < E){ myS[j]=src[e]; myD[j]=dst[e]; atomicAdd(&hist[myD[j]>>9],1); }
    else myD[j] = -1;
  }
  __syncthreads();
  if (t < NBMAX) sc[t] = (t < NB)? hist[t] : 0;
  __syncthreads();
  for (int st=1; st<NBMAX; st<<=1){
    int v = 0;
    if (t < NBMAX && t >= st) v = sc[t-st];
    __syncthreads();
    if (t < NBMAX) sc[t] += v;
    __syncthreads();
  }
  if (t < NB){
    int excl = (t>0)? sc[t-1] : 0;
    lbase[t] = excl; lcur[t] = excl;
    gbase[t] = atomicAdd(&bucketCur[t], hist[t]);
  }
  __syncthreads();
  #pragma unroll
  for (int j=0;j<16;j++){
    if (myD[j] >= 0){
      int b = myD[j] >> 9;
      int p = atomicAdd(&lcur[b], 1);
      ls[p] = myS[j]; ld[p] = myD[j];
    }
  }
  __syncthreads();
  for (int i=t;i<cnt;i+=256){
    int d = ld[i];
    int b = d >> 9;
    int pos = gbase[b] + (i - lbase[b]);   // bucket-contiguous coalesced runs
    pairS[pos] = ls[i];
    pairD[pos] = d;
  }
}

__global__ __launch_bounds__(256) void bucket_csr_kernel(
    const int* __restrict__ bucketBase, const int* __restrict__ pairS,
    const int* __restrict__ pairD, int N, int* __restrict__ off, int* __restrict__ adj)
{
  __shared__ int cnt[NPB];
  __shared__ int offl[NPB+1];
  __shared__ int s1[256];
  __shared__ int win[CAP];
  int b = blockIdx.x;
  int t = threadIdx.x;
  int node0 = b * NPB;
  int base = bucketBase[b], end = bucketBase[b+1];
  int ce = end - base;
  for (int i=t;i<NPB;i+=256) cnt[i]=0;
  __syncthreads();
  for (int i=t;i<ce;i+=256) atomicAdd(&cnt[pairD[base+i]-node0], 1);
  __syncthreads();
  int a0 = cnt[2*t], a1 = cnt[2*t+1];
  s1[t] = a0 + a1;
  __syncthreads();
  for (int st=1; st<256; st<<=1){
    int v = (t>=st)? s1[t-st] : 0;
    __syncthreads();
    s1[t] += v;
    __syncthreads();
  }
  int excl = (t>0)? s1[t-1] : 0;
  offl[2*t] = excl; offl[2*t+1] = excl + a0;
  if (t == 255) offl[NPB] = s1[255];
  __syncthreads();
  for (int i=t;i<NPB;i+=256){
    int node = node0 + i;
    if (node <= N) off[node] = base + offl[i];
  }
  __syncthreads();
  // offl reused as cursor
  if (ce <= CAP){
    for (int i=t;i<ce;i+=256){
      int d = pairD[base+i];
      int p = atomicAdd(&offl[d-node0], 1);
      win[p] = pairS[base+i];          // LDS scatter: random ~2-way, free
    }
    __syncthreads();
    for (int i=t;i<ce;i+=256) adj[base+i] = win[i];   // coalesced dump
  } else {
    for (int i=t;i<ce;i+=256){
      int d = pairD[base+i];
      int p = atomicAdd(&offl[d-node0], 1);
      adj[base+p] = pairS[base+i];     // overflow fallback (never for this input)
    }
  }
}

// ---------------- weight prep: dst[c][r] = bf16(src[r][c]) ----------------
__global__ __launch_bounds__(256) void prep_w_kernel(
    const float* __restrict__ Wp, const float* __restrict__ Wl0, const float* __restrict__ Wr0,
    const float* __restrict__ Wl1, const float* __restrict__ Wr1, const float* __restrict__ W1,
    ushort* __restrict__ Wpt, ushort* __restrict__ Wl0t, ushort* __restrict__ Wr0t,
    ushort* __restrict__ Wl1t, ushort* __restrict__ Wr1t, ushort* __restrict__ W1t)
{
  const float* src; ushort* dst; int rows, cols;
  switch (blockIdx.y){
    case 0: src=Wp;  dst=Wpt;  rows=256; cols=128; break;
    case 1: src=Wl0; dst=Wl0t; rows=256; cols=128; break;
    case 2: src=Wr0; dst=Wr0t; rows=256; cols=128; break;
    case 3: src=Wl1; dst=Wl1t; rows=128; cols=128; break;
    case 4: src=Wr1; dst=Wr1t; rows=128; cols=128; break;
    default:src=W1;  dst=W1t;  rows=128; cols=64;  break;
  }
  int idx = blockIdx.x*256 + threadIdx.x;
  if (idx >= rows*cols) return;
  int r = idx / cols, c = idx - r*cols;
  dst[c*rows + r] = f2b(src[idx]);
}

// ---------------- multi-output bf16 MFMA GEMM: Ym = A @ Wm (+bias on mat0) ----------------
// 64 rows x 128 cols x NMAT mats per block; A read ONCE. 4 waves, wave w owns rows w*16..+15.
template<int K, int NMAT, bool AFP32>
__global__ __launch_bounds__(256) void gemm_mfma_multi(
    const void* __restrict__ Av, int nrows,
    const ushort* __restrict__ Wt0, const ushort* __restrict__ Wt1, const ushort* __restrict__ Wt2,
    const float* __restrict__ bias0,
    ushort* __restrict__ Y0, ushort* __restrict__ Y1, ushort* __restrict__ Y2)
{
  __shared__ __align__(16) ushort As[64][40];
  __shared__ __align__(16) ushort Bs[NMAT][128][40];
  int t = threadIdx.x;
  int w = t>>6, lane = t&63, lq = lane&15, quad = lane>>4, qk = quad*8;
  int row0 = blockIdx.x*64;
  // A staging: 4 threads/row, 8 elems each
  int ar = t>>2, akp = (t&3)*8;
  int garow = row0 + ar; if (garow >= nrows) garow = nrows - 1;
  const float*  Af = (const float*)Av;
  const ushort* Ab = (const ushort*)Av;
  // B staging: 2 threads/col, 16 elems each (per mat)
  int bc = t>>1, bkp = (t&1)*16;

  float4v acc[NMAT][8];
  #pragma unroll
  for (int m=0;m<NMAT;m++)
    #pragma unroll
    for (int j=0;j<8;j++)
      #pragma unroll
      for (int r=0;r<4;r++) acc[m][j][r] = 0.f;

  for (int k0=0; k0<K; k0+=32){
    short8 av;
    if (AFP32){
      const float* p = Af + (size_t)garow*K + akp + k0;
      float4 f0 = *(const float4*)(p);
      float4 f1 = *(const float4*)(p+4);
      av[0]=(short)f2b(f0.x); av[1]=(short)f2b(f0.y); av[2]=(short)f2b(f0.z); av[3]=(short)f2b(f0.w);
      av[4]=(short)f2b(f1.x); av[5]=(short)f2b(f1.y); av[6]=(short)f2b(f1.z); av[7]=(short)f2b(f1.w);
    } else {
      av = *(const short8*)(Ab + (size_t)garow*K + akp + k0);
    }
    short8 bv0[NMAT], bv1[NMAT];
    #pragma unroll
    for (int m=0;m<NMAT;m++){
      const ushort* Wm = (m==0)? Wt0 : (m==1)? Wt1 : Wt2;
      const ushort* p = Wm + (size_t)bc*K + bkp + k0;
      bv0[m] = *(const short8*)p;
      bv1[m] = *(const short8*)(p+8);
    }
    __syncthreads();
    *(short8*)&As[ar][akp] = av;
    #pragma unroll
    for (int m=0;m<NMAT;m++){
      *(short8*)&Bs[m][bc][bkp]   = bv0[m];
      *(short8*)&Bs[m][bc][bkp+8] = bv1[m];
    }
    __syncthreads();
    short8 af = *(const short8*)&As[w*16 + lq][qk];
    #pragma unroll
    for (int nt=0; nt<8; nt++){
      #pragma unroll
      for (int m=0;m<NMAT;m++){
        short8 bf = *(const short8*)&Bs[m][nt*16 + lq][qk];
        acc[m][nt] = __builtin_amdgcn_mfma_f32_16x16x32_bf16(af, bf, acc[m][nt], 0,0,0);
      }
    }
  }

  #pragma unroll
  for (int m=0;m<NMAT;m++){
    ushort* Ym = (m==0)? Y0 : (m==1)? Y1 : Y2;
    #pragma unroll
    for (int r=0; r<4; r++){
      int row = row0 + w*16 + quad*4 + r;
      if (row < nrows){
        #pragma unroll
        for (int nt=0; nt<8; nt++){
          float v = acc[m][nt][r];
          if (m==0 && bias0) v += bias0[nt*16 + lq];
          Ym[(size_t)row*128 + nt*16 + lq] = f2b(v);
        }
      }
    }
  }
}

// ---------------- combine: out = bf16(relu(mean_agg + bias + root) + res) ----------------
__global__ __launch_bounds__(256) void combine_b_kernel(
    const ushort* __restrict__ aggsrc, const ushort* __restrict__ rootsrc,
    const ushort* __restrict__ ressrc, const float* __restrict__ bias,
    const int* __restrict__ off, const int* __restrict__ adj,
    ushort* __restrict__ out, int n)
{
  int t = threadIdx.x;
  int d = t & 63;
  int node = blockIdx.x*4 + (t >> 6);
  if (node >= n) return;
  int s = off[node], e = off[node+1];
  const unsigned* aggu = (const unsigned*)aggsrc;
  float a0 = 0.f, a1 = 0.f;
  int p = s;
  for (; p+4 <= e; p += 4){
    int j0 = adj[p], j1 = adj[p+1], j2 = adj[p+2], j3 = adj[p+3];
    unsigned v0 = aggu[(size_t)j0*64 + d];
    unsigned v1 = aggu[(size_t)j1*64 + d];
    unsigned v2 = aggu[(size_t)j2*64 + d];
    unsigned v3 = aggu[(size_t)j3*64 + d];
    a0 += (blo(v0)+blo(v1)) + (blo(v2)+blo(v3));
    a1 += (bhi(v0)+bhi(v1)) + (bhi(v2)+bhi(v3));
  }
  for (; p < e; p++){
    unsigned v = aggu[(size_t)adj[p]*64 + d];
    a0 += blo(v); a1 += bhi(v);
  }
  int cnt = e - s;
  float inv = 1.f / (float)((cnt > 1)? cnt : 1);
  unsigned rt = ((const unsigned*)rootsrc)[(size_t)node*64 + d];
  unsigned rs = ((const unsigned*)ressrc)[(size_t)node*64 + d];
  float o0 = fmaxf(a0*inv + bias[2*d]   + blo(rt), 0.f) + blo(rs);
  float o1 = fmaxf(a1*inv + bias[2*d+1] + bhi(rt), 0.f) + bhi(rs);
  ((unsigned*)out)[(size_t)node*64 + d] = (unsigned)f2b(o0) | ((unsigned)f2b(o1) << 16);
}

// ---------------- head GEMM fused with W2 dot + alpha mix ----------------
// s1 = relu(A@W1 + b1) [rows][64]; out[row] = a*rer + (1-a)*(s1 . W2 + b2)
__global__ __launch_bounds__(256) void gemm_final_kernel(
    const ushort* __restrict__ A, int nrows,
    const ushort* __restrict__ W1t, const float* __restrict__ b1,
    const float* __restrict__ W2, const float* __restrict__ b2,
    const float* __restrict__ alogit, const float* __restrict__ rer,
    float* __restrict__ out)
{
  __shared__ __align__(16) ushort As[64][40];
  __shared__ __align__(16) ushort Bs[64][40];
  int t = threadIdx.x;
  int w = t>>6, lane = t&63, lq = lane&15, quad = lane>>4, qk = quad*8;
  int row0 = blockIdx.x*64;
  int ar = t>>2, akp = (t&3)*8;
  int garow = row0 + ar; if (garow >= nrows) garow = nrows - 1;
  const ushort* Ap = A + (size_t)garow*128 + akp;
  int bc = t>>2, bkp = (t&3)*8;
  const ushort* Wq = W1t + (size_t)bc*128 + bkp;

  float4v acc[4];
  #pragma unroll
  for (int j=0;j<4;j++)
    #pragma unroll
    for (int r=0;r<4;r++) acc[j][r] = 0.f;

  #pragma unroll
  for (int k0=0; k0<128; k0+=32){
    short8 av = *(const short8*)(Ap + k0);
    short8 bv = *(const short8*)(Wq + k0);
    __syncthreads();
    *(short8*)&As[ar][akp] = av;
    *(short8*)&Bs[bc][bkp] = bv;
    __syncthreads();
    short8 af = *(const short8*)&As[w*16 + lq][qk];
    #pragma unroll
    for (int nt=0; nt<4; nt++){
      short8 bf = *(const short8*)&Bs[nt*16 + lq][qk];
      acc[nt] = __builtin_amdgcn_mfma_f32_16x16x32_bf16(af, bf, acc[nt], 0,0,0);
    }
  }

  float al = alogit[0];
  float a  = 1.f / (1.f + __expf(-al));
  float pw[4] = {0.f,0.f,0.f,0.f};
  #pragma unroll
  for (int nt=0; nt<4; nt++){
    int c = nt*16 + lq;
    float w2 = W2[c];
    float bb = b1[c];
    #pragma unroll
    for (int r=0; r<4; r++)
      pw[r] += fmaxf(acc[nt][r] + bb, 0.f) * w2;
  }
  #pragma unroll
  for (int mask=1; mask<16; mask<<=1){
    #pragma unroll
    for (int r=0; r<4; r++)
      pw[r] += __shfl_xor(pw[r], mask);
  }
  if (lq == 0){
    #pragma unroll
    for (int r=0; r<4; r++){
      int row = row0 + w*16 + quad*4 + r;
      if (row < nrows)
        out[row] = a * rer[row] + (1.f - a) * (pw[r] + b2[0]);
    }
  }
}

extern "C" void kernel_launch(void* const* d_in, const int* in_sizes, int n_in,
                              void* d_out, int out_size, void* d_ws, size_t ws_size,
                              hipStream_t stream)
{
  (void)n_in; (void)out_size; (void)ws_size;
  const float* x    = (const float*)d_in[0];
  const int*   ei   = (const int*)d_in[1];
  const float* rer  = (const float*)d_in[2];
  const float* Wp   = (const float*)d_in[3];
  const float* bp   = (const float*)d_in[4];
  const float* Wl0  = (const float*)d_in[5];
  const float* bl0  = (const float*)d_in[6];
  const float* Wr0  = (const float*)d_in[7];
  const float* Wl1  = (const float*)d_in[8];
  const float* bl1  = (const float*)d_in[9];
  const float* Wr1  = (const float*)d_in[10];
  const float* W1   = (const float*)d_in[11];
  const float* b1   = (const float*)d_in[12];
  const float* W2   = (const float*)d_in[13];
  const float* b2   = (const float*)d_in[14];
  const float* alogit = (const float*)d_in[15];

  const int N = in_sizes[2];      // 50000
  const int E = in_sizes[1] / 2;  // 800000
  const int* src = ei;
  const int* dst = ei + E;
  const int NB = (N + NPB - 1) / NPB;   // 98

  // workspace layout
  ushort* U = (ushort*)d_ws;
  ushort* xp  = U;                         // [N][128] residual; reused as h2
  ushort* xl0 = xp  + (size_t)N*DH;        // reused as hl1
  ushort* xr0 = xl0 + (size_t)N*DH;        // reused as hr1
  ushort* h   = xr0 + (size_t)N*DH;
  ushort* Wpt  = h    + (size_t)N*DH;
  ushort* Wl0t = Wpt  + 256*128;
  ushort* Wr0t = Wl0t + 256*128;
  ushort* Wl1t = Wr0t + 256*128;
  ushort* Wr1t = Wl1t + 128*128;
  ushort* W1t  = Wr1t + 128*128;
  int* I = (int*)(W1t + 128*64);
  int* bucketCnt  = I;                   // NBMAX
  int* bucketBase = bucketCnt + NBMAX;   // NBMAX+1
  int* bucketCur  = bucketBase + NBMAX + 1;
  int* off   = bucketCur + NBMAX;        // N+1
  int* pairS = off + (N+1);              // E
  int* pairD = pairS + E;                // E
  int* adj   = pairD + E;                // E

  // weight prep (independent)
  prep_w_kernel<<<dim3(128,6), 256, 0, stream>>>(Wp,Wl0,Wr0,Wl1,Wr1,W1,
                                                 Wpt,Wl0t,Wr0t,Wl1t,Wr1t,W1t);

  // CSR build, coalesced
  hipMemsetAsync(bucketCnt, 0, NBMAX*sizeof(int), stream);
  int gP = (E + EPB - 1) / EPB;   // 196
  bucket_hist_kernel<<<gP, 256, 0, stream>>>(dst, E, NB, bucketCnt);
  scan_buckets_kernel<<<1, NBMAX, 0, stream>>>(bucketCnt, NB, E, bucketBase, bucketCur, off, N);
  partition_kernel<<<gP, 256, 0, stream>>>(src, dst, E, NB, bucketCur, pairS, pairD);
  bucket_csr_kernel<<<NB, 256, 0, stream>>>(bucketBase, pairS, pairD, N, off, adj);

  int gx = (N + 63) / 64;   // 782
  // GEMM0 (A=x fp32, read once): xp = x@Wp+bp ; xl0 = x@Wl0 ; xr0 = x@Wr0
  gemm_mfma_multi<256,3,true><<<gx, 256, 0, stream>>>(x, N, Wpt, Wl0t, Wr0t, bp, xp, xl0, xr0);
  // h = relu(mean(xl0[nbrs]) + bl0 + xr0) + xp
  combine_b_kernel<<<(N+3)/4, 256, 0, stream>>>(xl0, xr0, xp, bl0, off, adj, h, N);

  // GEMM1 (A=h bf16, read once): hl1 = h@Wl1 ; hr1 = h@Wr1
  gemm_mfma_multi<128,2,false><<<gx, 256, 0, stream>>>(h, N, Wl1t, Wr1t, Wr1t, nullptr, xl0, xr0, xr0);
  // h2 = relu(mean(hl1[nbrs]) + bl1 + hr1) + h   (h2 -> xp)
  combine_b_kernel<<<(N+3)/4, 256, 0, stream>>>(xl0, xr0, h, bl1, off, adj, xp, N);

  // head fused: out = a*rer + (1-a)*(relu(xp@W1+b1) . W2 + b2)
  gemm_final_kernel<<<gx, 256, 0, stream>>>(xp, N, W1t, b1, W2, b2, alogit, rer, (float*)d_out);
}

// Round 5
// 305.973 us; speedup vs baseline: 1.0439x; 1.0439x over previous
//
#include <hip/hip_runtime.h>
#include <hip/hip_bf16.h>

// SAGE reranker, round 5: barrier-free weights-resident MFMA GEMMs.
// R3 (128-tile fused): 43.8us, occ 12%. R4 (64-tile): 72us — B-restaging doubled,
// MFMA-per-barrier halved. Fix: B lives in LDS ONCE per block (frag-packed, 64KB,
// conflict-free lane*16B reads), A-frags direct global->reg (8 outstanding), ZERO
// barriers in the row loop. GEMM0 reads fp32 x inline (convert pass deleted).

#define DIN 256
#define DH 128
#define NPB 512        // nodes per bucket (dst>>9)
#define NBMAX 128      // max buckets (N<=65536)
#define EPB 4096       // edges per partition block
#define CAP 14336      // LDS adj window capacity

typedef __attribute__((ext_vector_type(8))) short short8;
typedef __attribute__((ext_vector_type(4))) float float4v;

__device__ inline ushort f2b(float f){
  unsigned u = __float_as_uint(f);
  u = (u + 0x7fffu + ((u >> 16) & 1u)) >> 16;   // round-nearest-even
  return (ushort)u;
}
__device__ inline float blo(unsigned v){ return __uint_as_float(v << 16); }
__device__ inline float bhi(unsigned v){ return __uint_as_float(v & 0xffff0000u); }
__device__ inline short8 pack8(float4 f0, float4 f1){
  short8 v;
  v[0]=(short)f2b(f0.x); v[1]=(short)f2b(f0.y); v[2]=(short)f2b(f0.z); v[3]=(short)f2b(f0.w);
  v[4]=(short)f2b(f1.x); v[5]=(short)f2b(f1.y); v[6]=(short)f2b(f1.z); v[7]=(short)f2b(f1.w);
  return v;
}

// ---------------- CSR build (bucketed, coalesced writes only) ----------------
__global__ __launch_bounds__(256) void bucket_hist_kernel(
    const int* __restrict__ dst, int E, int NB, int* __restrict__ bucketCnt)
{
  __shared__ int hist[NBMAX];
  int t = threadIdx.x;
  for (int i=t;i<NB;i+=256) hist[i]=0;
  __syncthreads();
  int base = blockIdx.x * EPB;
  #pragma unroll
  for (int j=0;j<16;j++){
    int e = base + j*256 + t;
    if (e < E) atomicAdd(&hist[dst[e] >> 9], 1);
  }
  __syncthreads();
  for (int i=t;i<NB;i+=256) atomicAdd(&bucketCnt[i], hist[i]);
}

__global__ void scan_buckets_kernel(const int* __restrict__ bucketCnt, int NB, int E,
                                    int* __restrict__ bucketBase, int* __restrict__ bucketCur,
                                    int* __restrict__ off, int N)
{
  __shared__ int s[NBMAX];
  int t = threadIdx.x;  // NBMAX threads
  s[t] = (t < NB)? bucketCnt[t] : 0;
  __syncthreads();
  for (int st=1; st<NBMAX; st<<=1){
    int v = (t>=st)? s[t-st] : 0;
    __syncthreads();
    s[t] += v;
    __syncthreads();
  }
  int excl = (t>0)? s[t-1] : 0;
  if (t < NB){ bucketBase[t] = excl; bucketCur[t] = excl; }
  if (t == NB) bucketBase[NB] = E;
  if (t == 0) off[N] = E;
}

__global__ __launch_bounds__(256) void partition_kernel(
    const int* __restrict__ src, const int* __restrict__ dst, int E, int NB,
    int* __restrict__ bucketCur, int* __restrict__ pairS, int* __restrict__ pairD)
{
  __shared__ int hist[NBMAX], lbase[NBMAX], gbase[NBMAX], lcur[NBMAX], sc[NBMAX];
  __shared__ int ls[EPB], ld[EPB];
  int t = threadIdx.x;
  int base = blockIdx.x * EPB;
  int cnt = E - base; if (cnt > EPB) cnt = EPB;
  for (int i=t;i<NB;i+=256) hist[i]=0;
  __syncthreads();
  int myS[16], myD[16];
  #pragma unroll
  for (int j=0;j<16;j++){
    int e = base + j*256 + t;
    if (e < E){ myS[j]=src[e]; myD[j]=dst[e]; atomicAdd(&hist[myD[j]>>9],1); }
    else myD[j] = -1;
  }
  __syncthreads();
  if (t < NBMAX) sc[t] = (t < NB)? hist[t] : 0;
  __syncthreads();
  for (int st=1; st<NBMAX; st<<=1){
    int v = 0;
    if (t < NBMAX && t >= st) v = sc[t-st];
    __syncthreads();
    if (t < NBMAX) sc[t] += v;
    __syncthreads();
  }
  if (t < NB){
    int excl = (t>0)? sc[t-1] : 0;
    lbase[t] = excl; lcur[t] = excl;
    gbase[t] = atomicAdd(&bucketCur[t], hist[t]);
  }
  __syncthreads();
  #pragma unroll
  for (int j=0;j<16;j++){
    if (myD[j] >= 0){
      int b = myD[j] >> 9;
      int p = atomicAdd(&lcur[b], 1);
      ls[p] = myS[j]; ld[p] = myD[j];
    }
  }
  __syncthreads();
  for (int i=t;i<cnt;i+=256){
    int d = ld[i];
    int b = d >> 9;
    int pos = gbase[b] + (i - lbase[b]);   // bucket-contiguous coalesced runs
    pairS[pos] = ls[i];
    pairD[pos] = d;
  }
}

__global__ __launch_bounds__(256) void bucket_csr_kernel(
    const int* __restrict__ bucketBase, const int* __restrict__ pairS,
    const int* __restrict__ pairD, int N, int* __restrict__ off, int* __restrict__ adj)
{
  __shared__ int cnt[NPB];
  __shared__ int offl[NPB+1];
  __shared__ int s1[256];
  __shared__ int win[CAP];
  int b = blockIdx.x;
  int t = threadIdx.x;
  int node0 = b * NPB;
  int base = bucketBase[b], end = bucketBase[b+1];
  int ce = end - base;
  for (int i=t;i<NPB;i+=256) cnt[i]=0;
  __syncthreads();
  for (int i=t;i<ce;i+=256) atomicAdd(&cnt[pairD[base+i]-node0], 1);
  __syncthreads();
  int a0 = cnt[2*t], a1 = cnt[2*t+1];
  s1[t] = a0 + a1;
  __syncthreads();
  for (int st=1; st<256; st<<=1){
    int v = (t>=st)? s1[t-st] : 0;
    __syncthreads();
    s1[t] += v;
    __syncthreads();
  }
  int excl = (t>0)? s1[t-1] : 0;
  offl[2*t] = excl; offl[2*t+1] = excl + a0;
  if (t == 255) offl[NPB] = s1[255];
  __syncthreads();
  for (int i=t;i<NPB;i+=256){
    int node = node0 + i;
    if (node <= N) off[node] = base + offl[i];
  }
  __syncthreads();
  // offl reused as cursor
  if (ce <= CAP){
    for (int i=t;i<ce;i+=256){
      int d = pairD[base+i];
      int p = atomicAdd(&offl[d-node0], 1);
      win[p] = pairS[base+i];          // LDS scatter: random ~2-way, free
    }
    __syncthreads();
    for (int i=t;i<ce;i+=256) adj[base+i] = win[i];   // coalesced dump
  } else {
    for (int i=t;i<ce;i+=256){
      int d = pairD[base+i];
      int p = atomicAdd(&offl[d-node0], 1);
      adj[base+p] = pairS[base+i];     // overflow fallback (never for this input)
    }
  }
}

// ---------------- weight prep: dst[c][r] = bf16(src[r][c]) ----------------
__global__ __launch_bounds__(256) void prep_w_kernel(
    const float* __restrict__ Wp, const float* __restrict__ Wl0, const float* __restrict__ Wr0,
    const float* __restrict__ Wl1, const float* __restrict__ Wr1, const float* __restrict__ W1,
    ushort* __restrict__ Wpt, ushort* __restrict__ Wl0t, ushort* __restrict__ Wr0t,
    ushort* __restrict__ Wl1t, ushort* __restrict__ Wr1t, ushort* __restrict__ W1t)
{
  const float* src; ushort* dst; int rows, cols;
  switch (blockIdx.y){
    case 0: src=Wp;  dst=Wpt;  rows=256; cols=128; break;
    case 1: src=Wl0; dst=Wl0t; rows=256; cols=128; break;
    case 2: src=Wr0; dst=Wr0t; rows=256; cols=128; break;
    case 3: src=Wl1; dst=Wl1t; rows=128; cols=128; break;
    case 4: src=Wr1; dst=Wr1t; rows=128; cols=128; break;
    default:src=W1;  dst=W1t;  rows=128; cols=64;  break;
  }
  int idx = blockIdx.x*256 + threadIdx.x;
  if (idx >= rows*cols) return;
  int r = idx / cols, c = idx - r*cols;
  dst[c*rows + r] = f2b(src[idx]);
}

// ------------- weights-resident barrier-free GEMM: Ym = A @ Wm (+bias) -------------
// B frag-packed in LDS (NM*128*K*2 = 65536 B), loaded once. Each wave owns 16-row
// stripes via grid-stride chunk loop; A-frags direct global->reg; no loop barriers.
// NM==1: mat selected by blockIdx.y from {Wta,Wtb,Wtc}/{Ya,Yb,Yc}, bias on mat 0.
// NM==2: both Wta/Wtb computed from one A read (no bias).
template<int K, int NM, bool AFP32>
__global__ __launch_bounds__(256) void gemm_wres(
    const void* __restrict__ Av, int nrows, int nchunks,
    const ushort* __restrict__ Wta, const ushort* __restrict__ Wtb, const ushort* __restrict__ Wtc,
    const float* __restrict__ bias0,
    ushort* __restrict__ Ya, ushort* __restrict__ Yb, ushort* __restrict__ Yc)
{
  constexpr int KS = K / 32;            // MFMA k-steps
  constexpr int G  = 128 * (K / 8);     // 16B granules per mat
  __shared__ __align__(16) ushort Bs[NM * 128 * K];   // 65536 B for both instantiations

  int t = threadIdx.x;
  int lane = t & 63, w = t >> 6;
  int lq = lane & 15, quad = lane >> 4;

  const ushort* W0 = Wta; const ushort* W1 = Wtb;
  ushort* O0 = Ya; ushort* O1 = Yb;
  const float* bias = nullptr;
  if (NM == 1){
    int mat = blockIdx.y;
    W0 = (mat==0)? Wta : (mat==1)? Wtb : Wtc;
    O0 = (mat==0)? Ya  : (mat==1)? Yb  : Yc;
    if (mat == 0) bias = bias0;
  }

  // stage B frag-packed: granule g = (ks*8 + nt)*64 + lane; frag read = lane*16B (conflict-free)
  #pragma unroll
  for (int m=0; m<NM; m++){
    const ushort* Wm = (m==0)? W0 : W1;
    for (int i = t; i < G; i += 256){
      int ln = i & 63;
      int nt = (i >> 6) & 7;
      int ks = i >> 9;
      const ushort* s = Wm + (size_t)(nt*16 + (ln & 15))*K + ks*32 + (ln >> 4)*8;
      *(short8*)&Bs[(size_t)(m*G + i)*8] = *(const short8*)s;
    }
  }
  __syncthreads();   // the only barrier

  float badd[8];
  #pragma unroll
  for (int nt=0; nt<8; nt++) badd[nt] = bias ? bias[nt*16 + lq] : 0.f;

  const float*  Af = (const float*)Av;
  const ushort* Ab = (const ushort*)Av;

  for (int chunk = blockIdx.x; chunk < nchunks; chunk += gridDim.x){
    int row0 = chunk*64 + w*16;
    if (row0 >= nrows) continue;
    int arow = row0 + lq; if (arow >= nrows) arow = nrows - 1;

    short8 av[KS];
    #pragma unroll
    for (int ks=0; ks<KS; ks++){
      if (AFP32){
        const float* p = Af + (size_t)arow*K + ks*32 + quad*8;
        av[ks] = pack8(*(const float4*)p, *(const float4*)(p+4));
      } else {
        av[ks] = *(const short8*)(Ab + (size_t)arow*K + ks*32 + quad*8);
      }
    }

    float4v acc[NM][8];
    #pragma unroll
    for (int m=0;m<NM;m++)
      #pragma unroll
      for (int nt=0;nt<8;nt++)
        #pragma unroll
        for (int r=0;r<4;r++) acc[m][nt][r] = 0.f;

    #pragma unroll
    for (int ks=0; ks<KS; ks++){
      #pragma unroll
      for (int nt=0; nt<8; nt++){
        #pragma unroll
        for (int m=0; m<NM; m++){
          short8 bf = *(const short8*)&Bs[(size_t)(m*G + (ks*8 + nt)*64 + lane)*8];
          acc[m][nt] = __builtin_amdgcn_mfma_f32_16x16x32_bf16(av[ks], bf, acc[m][nt], 0,0,0);
        }
      }
    }

    #pragma unroll
    for (int m=0; m<NM; m++){
      ushort* Om = (m==0)? O0 : O1;
      #pragma unroll
      for (int nt=0; nt<8; nt++){
        #pragma unroll
        for (int r=0; r<4; r++){
          int row = row0 + quad*4 + r;
          if (row < nrows)
            Om[(size_t)row*128 + nt*16 + lq] = f2b(acc[m][nt][r] + ((m==0)? badd[nt] : 0.f));
        }
      }
    }
  }
}

// ---------------- combine: out = bf16(relu(mean_agg + bias + root) + res) ----------------
__global__ __launch_bounds__(256) void combine_b_kernel(
    const ushort* __restrict__ aggsrc, const ushort* __restrict__ rootsrc,
    const ushort* __restrict__ ressrc, const float* __restrict__ bias,
    const int* __restrict__ off, const int* __restrict__ adj,
    ushort* __restrict__ out, int n)
{
  int t = threadIdx.x;
  int d = t & 63;
  int node = blockIdx.x*4 + (t >> 6);
  if (node >= n) return;
  int s = off[node], e = off[node+1];
  const unsigned* aggu = (const unsigned*)aggsrc;
  float a0 = 0.f, a1 = 0.f;
  int p = s;
  for (; p+4 <= e; p += 4){
    int j0 = adj[p], j1 = adj[p+1], j2 = adj[p+2], j3 = adj[p+3];
    unsigned v0 = aggu[(size_t)j0*64 + d];
    unsigned v1 = aggu[(size_t)j1*64 + d];
    unsigned v2 = aggu[(size_t)j2*64 + d];
    unsigned v3 = aggu[(size_t)j3*64 + d];
    a0 += (blo(v0)+blo(v1)) + (blo(v2)+blo(v3));
    a1 += (bhi(v0)+bhi(v1)) + (bhi(v2)+bhi(v3));
  }
  for (; p < e; p++){
    unsigned v = aggu[(size_t)adj[p]*64 + d];
    a0 += blo(v); a1 += bhi(v);
  }
  int cnt = e - s;
  float inv = 1.f / (float)((cnt > 1)? cnt : 1);
  unsigned rt = ((const unsigned*)rootsrc)[(size_t)node*64 + d];
  unsigned rs = ((const unsigned*)ressrc)[(size_t)node*64 + d];
  float o0 = fmaxf(a0*inv + bias[2*d]   + blo(rt), 0.f) + blo(rs);
  float o1 = fmaxf(a1*inv + bias[2*d+1] + bhi(rt), 0.f) + bhi(rs);
  ((unsigned*)out)[(size_t)node*64 + d] = (unsigned)f2b(o0) | ((unsigned)f2b(o1) << 16);
}

// ---------------- head GEMM fused with W2 dot + alpha mix ----------------
__global__ __launch_bounds__(256) void gemm_final_kernel(
    const ushort* __restrict__ A, int nrows,
    const ushort* __restrict__ W1t, const float* __restrict__ b1,
    const float* __restrict__ W2, const float* __restrict__ b2,
    const float* __restrict__ alogit, const float* __restrict__ rer,
    float* __restrict__ out)
{
  __shared__ __align__(16) ushort As[64][40];
  __shared__ __align__(16) ushort Bs[64][40];
  int t = threadIdx.x;
  int w = t>>6, lane = t&63, lq = lane&15, quad = lane>>4, qk = quad*8;
  int row0 = blockIdx.x*64;
  int ar = t>>2, akp = (t&3)*8;
  int garow = row0 + ar; if (garow >= nrows) garow = nrows - 1;
  const ushort* Ap = A + (size_t)garow*128 + akp;
  int bc = t>>2, bkp = (t&3)*8;
  const ushort* Wq = W1t + (size_t)bc*128 + bkp;

  float4v acc[4];
  #pragma unroll
  for (int j=0;j<4;j++)
    #pragma unroll
    for (int r=0;r<4;r++) acc[j][r] = 0.f;

  #pragma unroll
  for (int k0=0; k0<128; k0+=32){
    short8 av = *(const short8*)(Ap + k0);
    short8 bv = *(const short8*)(Wq + k0);
    __syncthreads();
    *(short8*)&As[ar][akp] = av;
    *(short8*)&Bs[bc][bkp] = bv;
    __syncthreads();
    short8 af = *(const short8*)&As[w*16 + lq][qk];
    #pragma unroll
    for (int nt=0; nt<4; nt++){
      short8 bf = *(const short8*)&Bs[nt*16 + lq][qk];
      acc[nt] = __builtin_amdgcn_mfma_f32_16x16x32_bf16(af, bf, acc[nt], 0,0,0);
    }
  }

  float al = alogit[0];
  float a  = 1.f / (1.f + __expf(-al));
  float pw[4] = {0.f,0.f,0.f,0.f};
  #pragma unroll
  for (int nt=0; nt<4; nt++){
    int c = nt*16 + lq;
    float w2 = W2[c];
    float bb = b1[c];
    #pragma unroll
    for (int r=0; r<4; r++)
      pw[r] += fmaxf(acc[nt][r] + bb, 0.f) * w2;
  }
  #pragma unroll
  for (int mask=1; mask<16; mask<<=1){
    #pragma unroll
    for (int r=0; r<4; r++)
      pw[r] += __shfl_xor(pw[r], mask);
  }
  if (lq == 0){
    #pragma unroll
    for (int r=0; r<4; r++){
      int row = row0 + w*16 + quad*4 + r;
      if (row < nrows)
        out[row] = a * rer[row] + (1.f - a) * (pw[r] + b2[0]);
    }
  }
}

extern "C" void kernel_launch(void* const* d_in, const int* in_sizes, int n_in,
                              void* d_out, int out_size, void* d_ws, size_t ws_size,
                              hipStream_t stream)
{
  (void)n_in; (void)out_size; (void)ws_size;
  const float* x    = (const float*)d_in[0];
  const int*   ei   = (const int*)d_in[1];
  const float* rer  = (const float*)d_in[2];
  const float* Wp   = (const float*)d_in[3];
  const float* bp   = (const float*)d_in[4];
  const float* Wl0  = (const float*)d_in[5];
  const float* bl0  = (const float*)d_in[6];
  const float* Wr0  = (const float*)d_in[7];
  const float* Wl1  = (const float*)d_in[8];
  const float* bl1  = (const float*)d_in[9];
  const float* Wr1  = (const float*)d_in[10];
  const float* W1   = (const float*)d_in[11];
  const float* b1   = (const float*)d_in[12];
  const float* W2   = (const float*)d_in[13];
  const float* b2   = (const float*)d_in[14];
  const float* alogit = (const float*)d_in[15];

  const int N = in_sizes[2];      // 50000
  const int E = in_sizes[1] / 2;  // 800000
  const int* src = ei;
  const int* dst = ei + E;
  const int NB = (N + NPB - 1) / NPB;   // 98

  // workspace layout
  ushort* U = (ushort*)d_ws;
  ushort* xp  = U;                         // [N][128] residual; reused as h2
  ushort* xl0 = xp  + (size_t)N*DH;        // reused as hl1
  ushort* xr0 = xl0 + (size_t)N*DH;        // reused as hr1
  ushort* h   = xr0 + (size_t)N*DH;
  ushort* Wpt  = h    + (size_t)N*DH;
  ushort* Wl0t = Wpt  + 256*128;
  ushort* Wr0t = Wl0t + 256*128;
  ushort* Wl1t = Wr0t + 256*128;
  ushort* Wr1t = Wl1t + 128*128;
  ushort* W1t  = Wr1t + 128*128;
  int* I = (int*)(W1t + 128*64);
  int* bucketCnt  = I;                   // NBMAX
  int* bucketBase = bucketCnt + NBMAX;   // NBMAX+1
  int* bucketCur  = bucketBase + NBMAX + 1;
  int* off   = bucketCur + NBMAX;        // N+1
  int* pairS = off + (N+1);              // E
  int* pairD = pairS + E;                // E
  int* adj   = pairD + E;                // E

  // weight prep (independent)
  prep_w_kernel<<<dim3(128,6), 256, 0, stream>>>(Wp,Wl0,Wr0,Wl1,Wr1,W1,
                                                 Wpt,Wl0t,Wr0t,Wl1t,Wr1t,W1t);

  // CSR build, coalesced
  hipMemsetAsync(bucketCnt, 0, NBMAX*sizeof(int), stream);
  int gP = (E + EPB - 1) / EPB;   // 196
  bucket_hist_kernel<<<gP, 256, 0, stream>>>(dst, E, NB, bucketCnt);
  scan_buckets_kernel<<<1, NBMAX, 0, stream>>>(bucketCnt, NB, E, bucketBase, bucketCur, off, N);
  partition_kernel<<<gP, 256, 0, stream>>>(src, dst, E, NB, bucketCur, pairS, pairD);
  bucket_csr_kernel<<<NB, 256, 0, stream>>>(bucketBase, pairS, pairD, N, off, adj);

  int nchunks = (N + 63) / 64;   // 782

  // GEMM0 (weights-resident, A=x fp32 inline-packed): xp = x@Wp+bp ; xl0 = x@Wl0 ; xr0 = x@Wr0
  gemm_wres<256,1,true><<<dim3(170,3), 256, 0, stream>>>(x, N, nchunks,
      Wpt, Wl0t, Wr0t, bp, xp, xl0, xr0);
  // h = relu(mean(xl0[nbrs]) + bl0 + xr0) + xp
  combine_b_kernel<<<(N+3)/4, 256, 0, stream>>>(xl0, xr0, xp, bl0, off, adj, h, N);

  // GEMM1 (both mats resident, A=h bf16): hl1 = h@Wl1 ; hr1 = h@Wr1
  gemm_wres<128,2,false><<<dim3(512,1), 256, 0, stream>>>(h, N, nchunks,
      Wl1t, Wr1t, nullptr, nullptr, xl0, xr0, nullptr);
  // h2 = relu(mean(hl1[nbrs]) + bl1 + hr1) + h   (h2 -> xp)
  combine_b_kernel<<<(N+3)/4, 256, 0, stream>>>(xl0, xr0, h, bl1, off, adj, xp, N);

  // head fused: out = a*rer + (1-a)*(relu(xp@W1+b1) . W2 + b2)
  gemm_final_kernel<<<nchunks, 256, 0, stream>>>(xp, N, W1t, b1, W2, b2, alogit, rer, (float*)d_out);
}